// Round 1
// baseline (348.487 us; speedup 1.0000x reference)
//
#include <hip/hip_runtime.h>

// ProposalLayer: two 1x1 convs (channel GEMM, K=384, N=48) + bias + reg permute.
// M = 4*200*176 = 140800 pixels. fp32 VALU path (no fp32 MFMA on CDNA4).

#define C_IN   384
#define N_CLS  6
#define N_REG  42
#define N_OUT  48          // 6 cls + 42 reg
#define NY     200
#define NX     176
#define NPIX   (NY * NX)   // 35200
#define NBATCH 4
#define CLS_ELEMS (NBATCH * N_CLS * NPIX)   // 844800
#define TOTAL_PIX (NBATCH * NPIX)           // 140800

// Build Wt[k][o] (k-major, o contiguous -> s_load_dwordx16 friendly) and fused bias[o].
__global__ __launch_bounds__(256) void prep_weights(
    const float* __restrict__ Wc, const float* __restrict__ bc,
    const float* __restrict__ Wr, const float* __restrict__ br,
    float* __restrict__ Wt, float* __restrict__ bias) {
  int idx = blockIdx.x * 256 + threadIdx.x;
  if (idx < C_IN * N_OUT) {
    int k = idx / N_OUT;
    int o = idx - k * N_OUT;
    Wt[idx] = (o < N_CLS) ? Wc[o * C_IN + k] : Wr[(o - N_CLS) * C_IN + k];
  }
  if (idx < N_OUT) bias[idx] = (idx < N_CLS) ? bc[idx] : br[idx - N_CLS];
}

__global__ __launch_bounds__(256, 2) void proposal_main(
    const float* __restrict__ feat, const float* __restrict__ Wt,
    const float* __restrict__ bias, float* __restrict__ out) {
  const int pix = blockIdx.x * 256 + threadIdx.x;   // grid covers exactly TOTAL_PIX
  const int b = pix / NPIX;
  const int p = pix - b * NPIX;
  const float* __restrict__ f = feat + b * (C_IN * NPIX) + p;

  float acc[N_OUT];
#pragma unroll
  for (int o = 0; o < N_OUT; ++o) acc[o] = bias[o];   // uniform -> s_load

  constexpr int U = 8;   // prefetch depth: 8 dword loads in flight per wave
  float vbuf[U];
#pragma unroll
  for (int u = 0; u < U; ++u) vbuf[u] = f[u * NPIX];

  for (int k0 = 0; k0 < C_IN - U; k0 += U) {
    float vnext[U];
#pragma unroll
    for (int u = 0; u < U; ++u) vnext[u] = f[(k0 + U + u) * NPIX];
#pragma unroll
    for (int u = 0; u < U; ++u) {
      const float* __restrict__ w = Wt + (k0 + u) * N_OUT;  // wave-uniform
#pragma unroll
      for (int o = 0; o < N_OUT; ++o) acc[o] = fmaf(vbuf[u], w[o], acc[o]);
    }
#pragma unroll
    for (int u = 0; u < U; ++u) vbuf[u] = vnext[u];
  }
  {
    const int k0 = C_IN - U;
#pragma unroll
    for (int u = 0; u < U; ++u) {
      const float* __restrict__ w = Wt + (k0 + u) * N_OUT;
#pragma unroll
      for (int o = 0; o < N_OUT; ++o) acc[o] = fmaf(vbuf[u], w[o], acc[o]);
    }
  }

  // Epilogue.
  // cls_map (B,3,2,ny,nx) is layout-identical to cls_raw (B,6,ny,nx): o = c*2+y.
  float* __restrict__ out_cls = out;
  float* __restrict__ out_reg = out + CLS_ELEMS;
#pragma unroll
  for (int o = 0; o < N_CLS; ++o)
    out_cls[(b * N_CLS + o) * NPIX + p] = acc[o];
  // reg_raw row r = c*14 + d*2 + y ; reg_map offset = (((b*3+c)*2+y)*NPIX + p)*7 + d
#pragma unroll
  for (int r = 0; r < N_REG; ++r) {
    const int c = r / 14;
    const int d = (r - c * 14) >> 1;
    const int y = r & 1;
    out_reg[((b * 3 + c) * 2 + y) * (NPIX * 7) + p * 7 + d] = acc[N_CLS + r];
  }
}

extern "C" void kernel_launch(void* const* d_in, const int* in_sizes, int n_in,
                              void* d_out, int out_size, void* d_ws, size_t ws_size,
                              hipStream_t stream) {
  const float* feat = (const float*)d_in[0];
  const float* Wc   = (const float*)d_in[1];
  const float* bc   = (const float*)d_in[2];
  const float* Wr   = (const float*)d_in[3];
  const float* br   = (const float*)d_in[4];
  float* outp = (float*)d_out;

  float* Wt   = (float*)d_ws;                 // [C_IN][N_OUT] = 73728 B
  float* bias = Wt + C_IN * N_OUT;            // [N_OUT]

  hipLaunchKernelGGL(prep_weights, dim3((C_IN * N_OUT + 255) / 256), dim3(256), 0, stream,
                     Wc, bc, Wr, br, Wt, bias);
  hipLaunchKernelGGL(proposal_main, dim3(TOTAL_PIX / 256), dim3(256), 0, stream,
                     feat, Wt, bias, outp);
}

// Round 2
// 317.461 us; speedup vs baseline: 1.0977x; 1.0977x over previous
//
#include <hip/hip_runtime.h>

// ProposalLayer on MFMA: C[140800 x 48] = feat[140800 x 384] * W^T, + bias, + reg permute.
// Orientation per MFMA tile: D(16 outs x 16 pix) = A(W tile, 16x32) * B(feat, 32x16).
// C/D layout (m89-verified): col = lane&15 (pixel), row = (lane>>4)*4 + reg (output).
// A/B k-map chosen identically for both operands -> result invariant to HW k-order.

#define C_IN   384
#define NPIX   35200            // 200*176
#define NBATCH 4
#define N_OUT  48               // 6 cls + 42 reg
#define KSTEPS 12               // 384 / 32
#define WFRAG_ELEMS (KSTEPS * 3 * 64 * 8)   // 18432 bf16 = 36864 B
#define CLS_ELEMS (NBATCH * 6 * NPIX)       // 844800

typedef __attribute__((ext_vector_type(8))) short bf16x8;
typedef __attribute__((ext_vector_type(4))) float f32x4;

static __device__ __forceinline__ short f2bf(float f) {
  union { float f; unsigned u; } v; v.f = f;
  unsigned r = v.u + 0x7FFFu + ((v.u >> 16) & 1u);   // round-to-nearest-even
  return (short)(r >> 16);
}

// Pack weights into per-lane MFMA A-fragment order (bf16) + fused bias vector.
// Wfrag[((s*3 + t)*64 + lane)*8 + j] = W[o=t*16+(lane&15)][k=s*32+8*(lane>>4)+j]
__global__ __launch_bounds__(256) void prep_weights(
    const float* __restrict__ Wc, const float* __restrict__ bc,
    const float* __restrict__ Wr, const float* __restrict__ br,
    short* __restrict__ Wfrag, float* __restrict__ bias) {
  int idx = blockIdx.x * 256 + threadIdx.x;
  if (idx < WFRAG_ELEMS) {
    int j = idx & 7;
    int l = (idx >> 3) & 63;
    int t = (idx >> 9) % 3;
    int s = idx / 1536;
    int o = t * 16 + (l & 15);
    int k = s * 32 + 8 * (l >> 4) + j;
    float w = (o < 6) ? Wc[o * C_IN + k] : Wr[(o - 6) * C_IN + k];
    Wfrag[idx] = f2bf(w);
  }
  if (idx < N_OUT) bias[idx] = (idx < 6) ? bc[idx] : br[idx - 6];
}

__global__ __launch_bounds__(512) void proposal_mfma(
    const float* __restrict__ feat, const short* __restrict__ Wfrag,
    const float* __restrict__ bias, float* __restrict__ out) {
  __shared__ short wlds[WFRAG_ELEMS];   // 36864 B

  // Stage all weight fragments to LDS (coalesced 16B chunks): 2304 x 16B.
  {
    const f32x4* __restrict__ src = (const f32x4*)Wfrag;
    f32x4* dst = (f32x4*)wlds;
    for (int i = threadIdx.x; i < WFRAG_ELEMS / 8; i += 512) dst[i] = src[i];
  }

  const int lane = threadIdx.x & 63;
  const int wave = threadIdx.x >> 6;
  const int g  = lane >> 4;       // k-group
  const int lc = lane & 15;       // pixel within tile
  const int gp = blockIdx.x * 128 + wave * 16;   // global pixel tile base
  const int b  = gp / NPIX;       // uniform per block (128 divides 35200)
  const int p  = gp - b * NPIX;

  // Lane's feature base: k = s*32 + 8*g + j  ->  fbase[(s*32 + j)*NPIX]
  const float* __restrict__ fbase =
      feat + (size_t)(b * C_IN + 8 * g) * NPIX + p + lc;

  // Accumulators init from bias: acc[t][r] <-> output o = t*16 + 4*g + r.
  f32x4 acc[3];
#pragma unroll
  for (int t = 0; t < 3; ++t)
#pragma unroll
    for (int r = 0; r < 4; ++r) acc[t][r] = bias[t * 16 + 4 * g + r];

  __syncthreads();

  float fc[8], fn[8];
#pragma unroll
  for (int j = 0; j < 8; ++j) fc[j] = fbase[(size_t)j * NPIX];

  for (int s = 0; s < KSTEPS; ++s) {
    if (s + 1 < KSTEPS) {
#pragma unroll
      for (int j = 0; j < 8; ++j)
        fn[j] = fbase[(size_t)((s + 1) * 32 + j) * NPIX];
    }
    bf16x8 bf;
#pragma unroll
    for (int j = 0; j < 8; ++j) bf[j] = f2bf(fc[j]);
#pragma unroll
    for (int t = 0; t < 3; ++t) {
      bf16x8 af = *(const bf16x8*)(wlds + ((size_t)(s * 3 + t) * 64 + lane) * 8);
      acc[t] = __builtin_amdgcn_mfma_f32_16x16x32_bf16(af, bf, acc[t], 0, 0, 0);
    }
#pragma unroll
    for (int j = 0; j < 8; ++j) fc[j] = fn[j];
  }

  // Epilogue: o = t*16 + 4*g + r, pixel pp.
  const int pp = p + lc;
#pragma unroll
  for (int t = 0; t < 3; ++t)
#pragma unroll
    for (int r = 0; r < 4; ++r) {
      const int o = t * 16 + 4 * g + r;   // lane-group dependent
      const float v = acc[t][r];
      if (o < 6) {
        out[(size_t)(b * 6 + o) * NPIX + pp] = v;
      } else {
        const int q = o - 6;              // q = c*14 + d*2 + y
        const int c = q / 14;
        const int qq = q - c * 14;
        const int d = qq >> 1;
        const int y = qq & 1;
        out[CLS_ELEMS + (size_t)((b * 3 + c) * 2 + y) * (NPIX * 7)
            + (size_t)pp * 7 + d] = v;
      }
    }
}

extern "C" void kernel_launch(void* const* d_in, const int* in_sizes, int n_in,
                              void* d_out, int out_size, void* d_ws, size_t ws_size,
                              hipStream_t stream) {
  const float* feat = (const float*)d_in[0];
  const float* Wc   = (const float*)d_in[1];
  const float* bc   = (const float*)d_in[2];
  const float* Wr   = (const float*)d_in[3];
  const float* br   = (const float*)d_in[4];
  float* outp = (float*)d_out;

  short* Wfrag = (short*)d_ws;                       // 36864 B
  float* bias  = (float*)((char*)d_ws + WFRAG_ELEMS * sizeof(short));

  hipLaunchKernelGGL(prep_weights, dim3((WFRAG_ELEMS + 255) / 256), dim3(256),
                     0, stream, Wc, bc, Wr, br, Wfrag, bias);
  hipLaunchKernelGGL(proposal_mfma, dim3(140800 / 128), dim3(512), 0, stream,
                     feat, Wfrag, bias, outp);
}